// Round 1
// baseline (358.019 us; speedup 1.0000x reference)
//
#include <hip/hip_runtime.h>
#include <hip/hip_bf16.h>
#include <type_traits>

// Problem constants
#define BB 2
#define SS 2048
#define DD 1024
#define HH 16
#define DHH 64
#define MMR (BB*SS)   // 4096 rows

typedef __hip_bfloat16 bf;
typedef __bf16 bf16x8 __attribute__((ext_vector_type(8)));
typedef float f32x4 __attribute__((ext_vector_type(4)));

__device__ __forceinline__ f32x4 mfma16(bf16x8 a, bf16x8 b, f32x4 c) {
    return __builtin_amdgcn_mfma_f32_16x16x32_bf16(a, b, c, 0, 0, 0);
}

// ---------------------------------------------------------------
// f32 -> bf16 convert, 4 elems/thread, n divisible by 1024
__global__ __launch_bounds__(256) void k_f32_to_bf16(const float* __restrict__ src,
                                                     bf* __restrict__ dst) {
    int t = blockIdx.x * 256 + threadIdx.x;
    int j = t * 4;
    float4 v = *(const float4*)(src + j);
    bf tmp[4];
    tmp[0] = __float2bfloat16(v.x);
    tmp[1] = __float2bfloat16(v.y);
    tmp[2] = __float2bfloat16(v.z);
    tmp[3] = __float2bfloat16(v.w);
    *(uint2*)(dst + j) = *(const uint2*)tmp;
}

// ---------------------------------------------------------------
// C[m,n] = sum_k A[m,k] * Bt[n,k].  A:[M,K] bf16 row-major, Bt:[N,K] bf16 row-major.
// Tiles 64x64, BK=32, 256 threads (4 waves), wave w owns rows w*16..w*16+15.
template<typename OutT>
__global__ __launch_bounds__(256) void k_gemm_bt(const bf* __restrict__ A,
                                                 const bf* __restrict__ Bt,
                                                 OutT* __restrict__ C,
                                                 int M, int N, int K) {
    __shared__ __align__(16) bf Asm[64 * 32];
    __shared__ __align__(16) bf Bsm[64 * 32];
    const int tid  = threadIdx.x;
    const int w    = tid >> 6;
    const int lane = tid & 63;
    const int g    = lane >> 4;   // 0..3
    const int rl   = lane & 15;   // 0..15
    const int m0 = blockIdx.y * 64;
    const int n0 = blockIdx.x * 64;
    const int srow = tid >> 2;    // 0..63 staging row
    const int sseg = tid & 3;     // 16B segment

    f32x4 acc[4] = {f32x4{0,0,0,0}, f32x4{0,0,0,0}, f32x4{0,0,0,0}, f32x4{0,0,0,0}};

    for (int k0 = 0; k0 < K; k0 += 32) {
        __syncthreads();
        const int4 av = *(const int4*)(A + (size_t)(m0 + srow) * K + k0 + sseg * 8);
        const int4 bv = *(const int4*)(Bt + (size_t)(n0 + srow) * K + k0 + sseg * 8);
        ((int4*)Asm)[tid] = av;   // tid == srow*4 + sseg
        ((int4*)Bsm)[tid] = bv;
        __syncthreads();

        bf16x8 a = __builtin_bit_cast(bf16x8, ((const int4*)Asm)[(w * 16 + rl) * 4 + g]);
#pragma unroll
        for (int nt = 0; nt < 4; ++nt) {
            bf16x8 b = __builtin_bit_cast(bf16x8, ((const int4*)Bsm)[(nt * 16 + rl) * 4 + g]);
            acc[nt] = mfma16(a, b, acc[nt]);
        }
    }

#pragma unroll
    for (int nt = 0; nt < 4; ++nt) {
#pragma unroll
        for (int ri = 0; ri < 4; ++ri) {
            int m = m0 + w * 16 + g * 4 + ri;
            int n = n0 + nt * 16 + rl;
            float v = acc[nt][ri];
            OutT* p = C + (size_t)m * N + n;
            if constexpr (std::is_same<OutT, float>::value) *p = v;
            else *p = __float2bfloat16(v);
        }
    }
}

// ---------------------------------------------------------------
// Normalize Q,K rows per (b,h,s) over DH=64 and reshape [B*S,D] -> [B*H,S,64]
__global__ __launch_bounds__(256) void k_norm_qk(const bf* __restrict__ Qb,
                                                 const bf* __restrict__ Kb,
                                                 bf* __restrict__ Qn,
                                                 bf* __restrict__ Kn) {
    const int bs = blockIdx.x;            // b*S + s
    const int b = bs >> 11;               // /S (2048)
    const int s = bs & 2047;
    const int w = threadIdx.x >> 6;
    const int lane = threadIdx.x & 63;
#pragma unroll
    for (int i = 0; i < 4; ++i) {
        const int h = w * 4 + i;
        const size_t src = (size_t)bs * DD + h * 64 + lane;
        const size_t dst = ((size_t)(b * HH + h) * SS + s) * 64 + lane;
        {
            float v = __bfloat162float(Qb[src]);
            float ss = v * v;
#pragma unroll
            for (int d = 1; d < 64; d <<= 1) ss += __shfl_xor(ss, d, 64);
            Qn[dst] = __float2bfloat16(v * rsqrtf(ss));
        }
        {
            float v = __bfloat162float(Kb[src]);
            float ss = v * v;
#pragma unroll
            for (int d = 1; d < 64; d <<= 1) ss += __shfl_xor(ss, d, 64);
            Kn[dst] = __float2bfloat16(v * rsqrtf(ss));
        }
    }
}

// ---------------------------------------------------------------
// V: [B*S, D] -> Vt: [B*H, 64, S]
__global__ __launch_bounds__(256) void k_transpose_v(const bf* __restrict__ Vb,
                                                     bf* __restrict__ Vt) {
    __shared__ bf tile[64][65];
    const int by = blockIdx.y;            // b*H + h
    const int b = by >> 4, h = by & 15;
    const int s0 = blockIdx.x * 64;
    for (int i = threadIdx.x; i < 64 * 64; i += 256) {
        int sl = i >> 6, dl = i & 63;
        tile[dl][sl] = Vb[(size_t)(b * SS + s0 + sl) * DD + h * 64 + dl];
    }
    __syncthreads();
    for (int i = threadIdx.x; i < 64 * 64; i += 256) {
        int dl = i >> 6, sl = i & 63;
        Vt[((size_t)by * 64 + dl) * SS + s0 + sl] = tile[dl][sl];
    }
}

// ---------------------------------------------------------------
// Attention: per (b,h, q-tile of 64). 4 waves, wave w handles 16 q rows.
// scores = Qn.Kn^T, relu+causal+pad-mask, att(bf16) @ V -> ctx [B*S, D] merged.
__global__ __launch_bounds__(256) void k_attn(const bf* __restrict__ Qn,  // [B*H,S,64]
                                              const bf* __restrict__ Kn,  // [B*H,S,64]
                                              const bf* __restrict__ Vt,  // [B*H,64,S]
                                              const int* __restrict__ masks, // [B,S]
                                              bf* __restrict__ Ctx) {     // [B*S, D]
    __shared__ __align__(16) bf attS[4][16][40];  // per-wave 16x32 (+8 pad)

    const int qt = blockIdx.x;
    const int by = blockIdx.y;            // b*H + h
    const int b = by >> 4, h = by & 15;
    const int tid = threadIdx.x;
    const int w = tid >> 6;
    const int lane = tid & 63;
    const int g = lane >> 4;
    const int rl = lane & 15;
    const int q0 = qt * 64;
    const int qw = q0 + w * 16;           // wave's first q row

    const bf* Qp = Qn + (size_t)by * SS * 64;
    const bf* Kp = Kn + (size_t)by * SS * 64;
    const bf* Vp = Vt + (size_t)by * 64 * SS;
    const int* mrow = masks + b * SS;

    // Q fragments (A operand), hoisted
    bf16x8 aq[2];
#pragma unroll
    for (int ks = 0; ks < 2; ++ks) {
        int4 t = *(const int4*)(Qp + (size_t)(qw + rl) * 64 + ks * 32 + g * 8);
        aq[ks] = __builtin_bit_cast(bf16x8, t);
    }

    f32x4 acc[4] = {f32x4{0,0,0,0}, f32x4{0,0,0,0}, f32x4{0,0,0,0}, f32x4{0,0,0,0}};

    const int nk = qw + 16;               // exclusive causal bound for this wave
    for (int k0 = 0; k0 < nk; k0 += 32) {
        // ---- QK^T: 16 q x 32 k
        f32x4 sc[2] = {f32x4{0,0,0,0}, f32x4{0,0,0,0}};
#pragma unroll
        for (int nt = 0; nt < 2; ++nt) {
#pragma unroll
            for (int ks = 0; ks < 2; ++ks) {
                int4 t = *(const int4*)(Kp + (size_t)(k0 + nt * 16 + rl) * 64 + ks * 32 + g * 8);
                bf16x8 bk = __builtin_bit_cast(bf16x8, t);
                sc[nt] = mfma16(aq[ks], bk, sc[nt]);
            }
        }
        // ---- relu + causal + key-pad mask, write bf16 att to wave-private LDS
#pragma unroll
        for (int nt = 0; nt < 2; ++nt) {
            const int k = k0 + nt * 16 + rl;
            const int mvalid = mrow[k];
#pragma unroll
            for (int ri = 0; ri < 4; ++ri) {
                const int q = qw + g * 4 + ri;
                float v = sc[nt][ri];
                v = fmaxf(v, 0.0f);
                if (k > q || !mvalid) v = 0.0f;
                attS[w][g * 4 + ri][nt * 16 + rl] = __float2bfloat16(v);
            }
        }
        __threadfence_block();   // order ds_write -> ds_read (wave-internal)
        // ---- PV: att(16x32) @ V(32x64)
        bf16x8 pa = __builtin_bit_cast(bf16x8, *(const int4*)(&attS[w][rl][g * 8]));
#pragma unroll
        for (int nt = 0; nt < 4; ++nt) {
            int4 tv = *(const int4*)(Vp + (size_t)(nt * 16 + rl) * SS + k0 + g * 8);
            bf16x8 bv = __builtin_bit_cast(bf16x8, tv);
            acc[nt] = mfma16(pa, bv, acc[nt]);
        }
        __threadfence_block();   // order this iter's ds_read before next iter's ds_write
    }

    // epilogue: zero padded queries, write merged ctx bf16 [b*S+q][h*64+d]
#pragma unroll
    for (int ri = 0; ri < 4; ++ri) {
        const int q = qw + g * 4 + ri;
        const float mq = mrow[q] ? 1.0f : 0.0f;
#pragma unroll
        for (int nt = 0; nt < 4; ++nt) {
            Ctx[(size_t)(b * SS + q) * DD + h * 64 + nt * 16 + rl] =
                __float2bfloat16(acc[nt][ri] * mq);
        }
    }
}

// ---------------------------------------------------------------
extern "C" void kernel_launch(void* const* d_in, const int* in_sizes, int n_in,
                              void* d_out, int out_size, void* d_ws, size_t ws_size,
                              hipStream_t stream) {
    const float* X  = (const float*)d_in[0];
    const int* masks = (const int*)d_in[1];
    const float* Wq = (const float*)d_in[2];
    const float* Wk = (const float*)d_in[3];
    const float* Wv = (const float*)d_in[4];
    const float* Wo = (const float*)d_in[5];
    float* out = (float*)d_out;
    char* ws = (char*)d_ws;

    const size_t MB = 1024 * 1024;
    bf* Xb  = (bf*)(ws);              // 8 MB
    bf* Wqb = (bf*)(ws + 8  * MB);    // 2 MB
    bf* Wkb = (bf*)(ws + 10 * MB);
    bf* Wvb = (bf*)(ws + 12 * MB);
    bf* Wob = (bf*)(ws + 14 * MB);
    bf* Qb  = (bf*)(ws + 16 * MB);    // 8 MB  [B*S, D]
    bf* Kb  = (bf*)(ws + 24 * MB);
    bf* Vb  = (bf*)(ws + 32 * MB);
    bf* Qn  = (bf*)(ws + 40 * MB);    // 8 MB  [B*H, S, 64]
    bf* Kn  = (bf*)(ws + 48 * MB);
    bf* Vt  = (bf*)(ws + 56 * MB);    // 8 MB  [B*H, 64, S]
    bf* Ctx = (bf*)(ws + 64 * MB);    // 8 MB  [B*S, D]

    // converts
    k_f32_to_bf16<<<MMR * DD / 1024, 256, 0, stream>>>(X, Xb);
    k_f32_to_bf16<<<DD * DD / 1024, 256, 0, stream>>>(Wq, Wqb);
    k_f32_to_bf16<<<DD * DD / 1024, 256, 0, stream>>>(Wk, Wkb);
    k_f32_to_bf16<<<DD * DD / 1024, 256, 0, stream>>>(Wv, Wvb);
    k_f32_to_bf16<<<DD * DD / 1024, 256, 0, stream>>>(Wo, Wob);

    // QKV projections
    dim3 gg(DD / 64, MMR / 64);  // (16, 64)
    k_gemm_bt<bf><<<gg, 256, 0, stream>>>(Xb, Wqb, Qb, MMR, DD, DD);
    k_gemm_bt<bf><<<gg, 256, 0, stream>>>(Xb, Wkb, Kb, MMR, DD, DD);
    k_gemm_bt<bf><<<gg, 256, 0, stream>>>(Xb, Wvb, Vb, MMR, DD, DD);

    // normalize + reshape
    k_norm_qk<<<MMR, 256, 0, stream>>>(Qb, Kb, Qn, Kn);

    // V transpose
    k_transpose_v<<<dim3(SS / 64, BB * HH), 256, 0, stream>>>(Vb, Vt);

    // attention
    k_attn<<<dim3(SS / 64, BB * HH), 256, 0, stream>>>(Qn, Kn, Vt, masks, Ctx);

    // output projection (f32 out)
    k_gemm_bt<float><<<gg, 256, 0, stream>>>(Ctx, Wob, out, MMR, DD, DD);
}

// Round 2
// 149.615 us; speedup vs baseline: 2.3929x; 2.3929x over previous
//
#include <hip/hip_runtime.h>
#include <hip/hip_bf16.h>
#include <type_traits>

// Problem constants
#define BB 2
#define SS 2048
#define DD 1024
#define HH 16
#define MMR (BB*SS)   // 4096 rows
#define ND3 3072      // fused QKV width

typedef __hip_bfloat16 bf;
typedef __bf16 bf16x8 __attribute__((ext_vector_type(8)));
typedef float f32x4 __attribute__((ext_vector_type(4)));

__device__ __forceinline__ f32x4 mfma16(bf16x8 a, bf16x8 b, f32x4 c) {
    return __builtin_amdgcn_mfma_f32_16x16x32_bf16(a, b, c, 0, 0, 0);
}

// async global->LDS, 16B per lane; LDS dest = wave-uniform base + lane*16
__device__ __forceinline__ void glds16(const bf* g, bf* l) {
    __builtin_amdgcn_global_load_lds(
        (const __attribute__((address_space(1))) void*)g,
        (__attribute__((address_space(3))) void*)l,
        16, 0, 0);
}

// ---------------------------------------------------------------
// f32 -> bf16 convert, 4 elems/thread
__global__ __launch_bounds__(256) void k_f32_to_bf16(const float* __restrict__ src,
                                                     bf* __restrict__ dst) {
    int t = blockIdx.x * 256 + threadIdx.x;
    int j = t * 4;
    float4 v = *(const float4*)(src + j);
    bf tmp[4];
    tmp[0] = __float2bfloat16(v.x);
    tmp[1] = __float2bfloat16(v.y);
    tmp[2] = __float2bfloat16(v.z);
    tmp[3] = __float2bfloat16(v.w);
    *(uint2*)(dst + j) = *(const uint2*)tmp;
}

// ---------------------------------------------------------------
// m97-style 128x128 tile GEMM, BK=32: C[m,n] = sum_k A[m,k]*Bt[n,k]
// 256 threads (4 waves), wave w -> 64x64 quadrant (wr,wc), 16 MFMA / K-step.
template<typename OutT>
__global__ __launch_bounds__(256) void k_gemm128(const bf* __restrict__ A,
                                                 const bf* __restrict__ Bt,
                                                 OutT* __restrict__ C,
                                                 int M, int N, int K) {
    __shared__ __align__(16) bf Asm[128 * 32];
    __shared__ __align__(16) bf Bsm[128 * 32];
    const int tid = threadIdx.x;
    const int w = tid >> 6, lane = tid & 63, g = lane >> 4, rl = lane & 15;
    const int m0 = blockIdx.y * 128, n0 = blockIdx.x * 128;
    const int wr = (w >> 1) * 64, wc = (w & 1) * 64;
    const int srow = lane >> 2, sseg = lane & 3;   // within 16-row chunk

    f32x4 acc[4][4] = {};

    const bf* Ap = A + (size_t)m0 * K;
    const bf* Bp = Bt + (size_t)n0 * K;

    for (int k0 = 0; k0 < K; k0 += 32) {
        __syncthreads();   // previous iter's fragment reads done before overwrite
#pragma unroll
        for (int u = 0; u < 2; ++u) {
            const int c = w * 2 + u;             // chunk 0..7 = 16 rows x 64B
            const int row = c * 16 + srow;
            glds16(Ap + (size_t)row * K + k0 + sseg * 8, &Asm[c * 512]);
            glds16(Bp + (size_t)row * K + k0 + sseg * 8, &Bsm[c * 512]);
        }
        __syncthreads();   // drains vmcnt(0): staged data visible

        bf16x8 af[4], bfr[4];
#pragma unroll
        for (int m = 0; m < 4; ++m)
            af[m] = __builtin_bit_cast(bf16x8, *(const int4*)&Asm[(wr + m * 16 + rl) * 32 + g * 8]);
#pragma unroll
        for (int n = 0; n < 4; ++n)
            bfr[n] = __builtin_bit_cast(bf16x8, *(const int4*)&Bsm[(wc + n * 16 + rl) * 32 + g * 8]);
#pragma unroll
        for (int m = 0; m < 4; ++m)
#pragma unroll
            for (int n = 0; n < 4; ++n)
                acc[m][n] = mfma16(af[m], bfr[n], acc[m][n]);
    }

#pragma unroll
    for (int m = 0; m < 4; ++m)
#pragma unroll
        for (int n = 0; n < 4; ++n)
#pragma unroll
            for (int ri = 0; ri < 4; ++ri) {
                const int mm = m0 + wr + m * 16 + g * 4 + ri;
                const int nn = n0 + wc + n * 16 + rl;
                if constexpr (std::is_same<OutT, float>::value)
                    C[(size_t)mm * N + nn] = acc[m][n][ri];
                else
                    C[(size_t)mm * N + nn] = __float2bfloat16(acc[m][n][ri]);
            }
}

// ---------------------------------------------------------------
// Normalize Q,K rows, FOLD PAD MASKS (zero invalid rows), reshape to [B*H,S,64]
__global__ __launch_bounds__(256) void k_norm_qk(const bf* __restrict__ QKV,
                                                 const int* __restrict__ masks,
                                                 bf* __restrict__ Qn,
                                                 bf* __restrict__ Kn) {
    const int bs = blockIdx.x;            // b*S + s
    const int b = bs >> 11, s = bs & 2047;
    const int w = threadIdx.x >> 6, lane = threadIdx.x & 63;
    const float mval = masks[bs] ? 1.0f : 0.0f;
#pragma unroll
    for (int i = 0; i < 4; ++i) {
        const int h = w * 4 + i;
        const size_t src = (size_t)bs * ND3 + h * 64 + lane;
        const size_t dst = ((size_t)(b * HH + h) * SS + s) * 64 + lane;
        {
            float v = __bfloat162float(QKV[src]);
            float ss2 = v * v;
#pragma unroll
            for (int d = 1; d < 64; d <<= 1) ss2 += __shfl_xor(ss2, d, 64);
            Qn[dst] = __float2bfloat16(v * rsqrtf(ss2) * mval);
        }
        {
            float v = __bfloat162float(QKV[src + 1024]);
            float ss2 = v * v;
#pragma unroll
            for (int d = 1; d < 64; d <<= 1) ss2 += __shfl_xor(ss2, d, 64);
            Kn[dst] = __float2bfloat16(v * rsqrtf(ss2) * mval);
        }
    }
}

// ---------------------------------------------------------------
// V slice of QKV: [B*S, 3072] -> Vt: [B*H, 64, S]
__global__ __launch_bounds__(256) void k_transpose_v(const bf* __restrict__ QKV,
                                                     bf* __restrict__ Vt) {
    __shared__ bf tile[64][65];
    const int by = blockIdx.y;            // b*H + h
    const int b = by >> 4, h = by & 15;
    const int s0 = blockIdx.x * 64;
    for (int i = threadIdx.x; i < 64 * 64; i += 256) {
        int sl = i >> 6, dl = i & 63;
        tile[dl][sl] = QKV[(size_t)(b * SS + s0 + sl) * ND3 + 2048 + h * 64 + dl];
    }
    __syncthreads();
    for (int i = threadIdx.x; i < 64 * 64; i += 256) {
        int dl = i >> 6, sl = i & 63;
        Vt[((size_t)by * 64 + dl) * SS + s0 + sl] = tile[dl][sl];
    }
}

// ---------------------------------------------------------------
// Attention: block = (q-tile 64, b*h). 4 waves x 16 q rows. KVBLK=64 staged in
// LDS (XOR-swizzled via pre-swizzled glds source), double-buffered.
// Swapped QK^T (mfma(K,Q)) -> lane owns P[q][k-run] -> packed bf16 P in LDS.
// Pad masks pre-folded into Qn/Kn (zero rows); causal only on diagonal tile.
__global__ __launch_bounds__(256) void k_attn(const bf* __restrict__ Qn,  // [B*H,S,64]
                                              const bf* __restrict__ Kn,  // [B*H,S,64]
                                              const bf* __restrict__ Vt,  // [B*H,64,S]
                                              bf* __restrict__ Ctx) {     // [B*S, D]
    __shared__ __align__(16) bf Ksm[2][64 * 64];  // [kv][d], row-XOR swizzled
    __shared__ __align__(16) bf Vsm[2][64 * 64];  // [d][kv], row-XOR swizzled
    __shared__ __align__(16) bf Psm[4][16 * 64];  // per-wave P[q][k], swizzled

    const int qt = blockIdx.x;
    const int by = blockIdx.y;            // b*H + h
    const int b = by >> 4, h = by & 15;
    const int tid = threadIdx.x;
    const int w = tid >> 6, lane = tid & 63, g = lane >> 4, rl = lane & 15;
    const int q0 = qt * 64, qw = q0 + w * 16;

    const bf* Qp = Qn + (size_t)by * SS * 64;
    const bf* Kp = Kn + (size_t)by * SS * 64;
    const bf* Vp = Vt + (size_t)by * 64 * SS;

    // hoisted Q fragments (B-operand of swapped QK^T)
    bf16x8 aq[2];
#pragma unroll
    for (int ks = 0; ks < 2; ++ks)
        aq[ks] = __builtin_bit_cast(bf16x8,
            *(const int4*)(Qp + (size_t)(qw + rl) * 64 + ks * 32 + g * 8));

    // staging geometry: chunk c = 8 rows x 128B; lane -> (row, 16B-block)
    const int srow = lane >> 3;                 // 0..7
    const int sblk = (lane & 7) ^ srow;         // pre-swizzled source block

    auto stage = [&](int buf, int k0) {
#pragma unroll
        for (int u = 0; u < 2; ++u) {
            const int c = w * 2 + u;
            const int row = c * 8 + srow;
            glds16(Kp + (size_t)(k0 + row) * 64 + sblk * 8, &Ksm[buf][c * 512]);
            glds16(Vp + (size_t)row * SS + k0 + sblk * 8, &Vsm[buf][c * 512]);
        }
    };

    f32x4 acc[4] = {};
    char* pbase = (char*)&Psm[w][0] + rl * 128;

    auto compute = [&](int buf, int k0, bool diag) {
        // ---- QK^T swapped: sc[nt] cols = q (rl), rows = k (g*4+ri)
        f32x4 sc[4] = {};
#pragma unroll
        for (int nt = 0; nt < 4; ++nt) {
            const int r = nt * 16 + rl;
#pragma unroll
            for (int ks = 0; ks < 2; ++ks) {
                bf16x8 ak = __builtin_bit_cast(bf16x8,
                    *(const int4*)&Ksm[buf][r * 64 + (((ks * 4 + g) ^ (rl & 7)) << 3)]);
                sc[nt] = mfma16(ak, aq[ks], sc[nt]);
            }
        }
        // ---- relu (+causal on diagonal tile), pack pairs, store P[q=rl][k]
#pragma unroll
        for (int nt = 0; nt < 4; ++nt) {
#pragma unroll
            for (int j = 0; j < 2; ++j) {
                float v0 = fmaxf(sc[nt][2 * j], 0.0f);
                float v1 = fmaxf(sc[nt][2 * j + 1], 0.0f);
                if (diag) {
                    const int q = qw + rl;
                    const int k = k0 + nt * 16 + g * 4 + 2 * j;
                    if (k > q) v0 = 0.0f;
                    if (k + 1 > q) v1 = 0.0f;
                }
                union { bf hh[2]; unsigned u; } p;
                p.hh[0] = __float2bfloat16(v0);
                p.hh[1] = __float2bfloat16(v1);
                const int blk16 = nt * 2 + (g >> 1);
                *(unsigned*)(pbase + (((blk16 ^ (rl & 7)) << 4) | ((g & 1) * 8 + 4 * j))) = p.u;
            }
        }
        __threadfence_block();   // wave-internal ds_write -> ds_read ordering
        // ---- PV: acc[nt] += P(16q x 32k) @ V(32k x 16d)
#pragma unroll
        for (int ks = 0; ks < 2; ++ks) {
            bf16x8 pa = __builtin_bit_cast(bf16x8,
                *(const int4*)(pbase + (((ks * 4 + g) ^ (rl & 7)) << 4)));
#pragma unroll
            for (int nt = 0; nt < 4; ++nt) {
                const int r = nt * 16 + rl;
                bf16x8 bv = __builtin_bit_cast(bf16x8,
                    *(const int4*)&Vsm[buf][r * 64 + (((ks * 4 + g) ^ (rl & 7)) << 3)]);
                acc[nt] = mfma16(pa, bv, acc[nt]);
            }
        }
    };

    const int ntile = qt + 1;          // causal: k-tiles 0..qt
    stage(0, 0);
    __syncthreads();                   // drains vmcnt(0)
    int cur = 0;
    for (int t = 0; t < ntile - 1; ++t) {
        stage(cur ^ 1, (t + 1) * 64);  // prefetch next tile
        compute(cur, t * 64, false);   // all sub-diagonal: no causal mask
        __syncthreads();               // drain prefetch + protect buffers
        cur ^= 1;
    }
    compute(cur, (ntile - 1) * 64, true);  // diagonal tile: causal mask

    // epilogue (query pad already folded into Qn -> acc rows are 0 for invalid q)
#pragma unroll
    for (int ri = 0; ri < 4; ++ri) {
        const int q = qw + g * 4 + ri;
#pragma unroll
        for (int nt = 0; nt < 4; ++nt) {
            Ctx[(size_t)(b * SS + q) * DD + h * 64 + nt * 16 + rl] =
                __float2bfloat16(acc[nt][ri]);
        }
    }
}

// ---------------------------------------------------------------
extern "C" void kernel_launch(void* const* d_in, const int* in_sizes, int n_in,
                              void* d_out, int out_size, void* d_ws, size_t ws_size,
                              hipStream_t stream) {
    const float* X  = (const float*)d_in[0];
    const int* masks = (const int*)d_in[1];
    const float* Wq = (const float*)d_in[2];
    const float* Wk = (const float*)d_in[3];
    const float* Wv = (const float*)d_in[4];
    const float* Wo = (const float*)d_in[5];
    float* out = (float*)d_out;
    char* ws = (char*)d_ws;

    const size_t MB = 1024 * 1024;
    bf* Xb   = (bf*)(ws);              // 8 MB  [B*S, D]
    bf* Wqkv = (bf*)(ws + 8  * MB);    // 6 MB  [3072, 1024] (q,k,v rows)
    bf* Wob  = (bf*)(ws + 14 * MB);    // 2 MB
    bf* QKV  = (bf*)(ws + 16 * MB);    // 24 MB [B*S, 3072]
    bf* Qn   = (bf*)(ws + 40 * MB);    // 8 MB  [B*H, S, 64]
    bf* Kn   = (bf*)(ws + 48 * MB);
    bf* Vt   = (bf*)(ws + 56 * MB);    // 8 MB  [B*H, 64, S]
    bf* Ctx  = (bf*)(ws + 64 * MB);    // 8 MB  [B*S, D]

    // converts (Wq/Wk/Wv concatenated into one [3072,1024] weight)
    k_f32_to_bf16<<<MMR * DD / 1024, 256, 0, stream>>>(X, Xb);
    k_f32_to_bf16<<<DD * DD / 1024, 256, 0, stream>>>(Wq, Wqkv);
    k_f32_to_bf16<<<DD * DD / 1024, 256, 0, stream>>>(Wk, Wqkv + 1024 * 1024);
    k_f32_to_bf16<<<DD * DD / 1024, 256, 0, stream>>>(Wv, Wqkv + 2 * 1024 * 1024);
    k_f32_to_bf16<<<DD * DD / 1024, 256, 0, stream>>>(Wo, Wob);

    // fused QKV projection: [4096,1024] @ [3072,1024]^T -> [4096,3072]
    k_gemm128<bf><<<dim3(ND3 / 128, MMR / 128), 256, 0, stream>>>(Xb, Wqkv, QKV, MMR, ND3, DD);

    // normalize + mask-fold + reshape
    k_norm_qk<<<MMR, 256, 0, stream>>>(QKV, masks, Qn, Kn);

    // V transpose
    k_transpose_v<<<dim3(SS / 64, BB * HH), 256, 0, stream>>>(QKV, Vt);

    // attention
    k_attn<<<dim3(SS / 64, BB * HH), 256, 0, stream>>>(Qn, Kn, Vt, Ctx);

    // output projection (f32 out)
    k_gemm128<float><<<dim3(DD / 128, MMR / 128), 256, 0, stream>>>(Ctx, Wob, out, MMR, DD, DD);
}

// Round 3
// 142.700 us; speedup vs baseline: 2.5089x; 1.0485x over previous
//
#include <hip/hip_runtime.h>
#include <hip/hip_bf16.h>

// Problem constants
#define BB 2
#define SS 2048
#define DD 1024
#define HH 16
#define MMR (BB*SS)   // 4096 rows
#define ND3 3072      // fused QKV width

typedef __hip_bfloat16 bf;
typedef __bf16 bf16x8 __attribute__((ext_vector_type(8)));
typedef float f32x4 __attribute__((ext_vector_type(4)));
typedef float f32x16 __attribute__((ext_vector_type(16)));

__device__ __forceinline__ f32x4 mfma16(bf16x8 a, bf16x8 b, f32x4 c) {
    return __builtin_amdgcn_mfma_f32_16x16x32_bf16(a, b, c, 0, 0, 0);
}
__device__ __forceinline__ f32x16 mfma32(bf16x8 a, bf16x8 b, f32x16 c) {
    return __builtin_amdgcn_mfma_f32_32x32x16_bf16(a, b, c, 0, 0, 0);
}
__device__ __forceinline__ unsigned cvt_pk_bf16(float lo, float hi) {
    unsigned r;
    asm("v_cvt_pk_bf16_f32 %0, %1, %2" : "=v"(r) : "v"(lo), "v"(hi));
    return r;
}
// after: a = {a.lo31, b.lo31}, b = {a.hi31, b.hi31}
__device__ __forceinline__ void pl32swap(unsigned& a, unsigned& b) {
    asm("v_permlane32_swap_b32 %0, %1" : "+v"(a), "+v"(b));
}
// async global->LDS, 16B/lane; LDS dest = wave-uniform base + lane*16
__device__ __forceinline__ void glds16(const bf* g, bf* l) {
    __builtin_amdgcn_global_load_lds(
        (const __attribute__((address_space(1))) void*)g,
        (__attribute__((address_space(3))) void*)l,
        16, 0, 0);
}

// ---------------------------------------------------------------
// f32 -> bf16, 4 elems/thread, 1024 elems/block
__global__ __launch_bounds__(256) void k_f32_to_bf16(const float* __restrict__ src,
                                                     bf* __restrict__ dst) {
    int j = (blockIdx.x * 256 + threadIdx.x) * 4;
    float4 v = *(const float4*)(src + j);
    bf tmp[4];
    tmp[0] = __float2bfloat16(v.x);
    tmp[1] = __float2bfloat16(v.y);
    tmp[2] = __float2bfloat16(v.z);
    tmp[3] = __float2bfloat16(v.w);
    *(uint2*)(dst + j) = *(const uint2*)tmp;
}

// 4 weight matrices (1M elems each) in one launch: region = blockIdx.x>>10
__global__ __launch_bounds__(256) void k_conv_w(const float* __restrict__ Wq,
                                                const float* __restrict__ Wk,
                                                const float* __restrict__ Wv,
                                                const float* __restrict__ Wo,
                                                bf* __restrict__ Wqkv,
                                                bf* __restrict__ Wob) {
    const int r = blockIdx.x >> 10;
    const float* src = (r == 0) ? Wq : (r == 1) ? Wk : (r == 2) ? Wv : Wo;
    bf* dst = (r < 3) ? (Wqkv + (size_t)r * 1048576) : Wob;
    int j = (((blockIdx.x & 1023) * 256) + threadIdx.x) * 4;
    float4 v = *(const float4*)(src + j);
    bf tmp[4];
    tmp[0] = __float2bfloat16(v.x);
    tmp[1] = __float2bfloat16(v.y);
    tmp[2] = __float2bfloat16(v.z);
    tmp[3] = __float2bfloat16(v.w);
    *(uint2*)(dst + j) = *(const uint2*)tmp;
}

// ---------------------------------------------------------------
// 128x128-tile GEMM, BK=32, 4 waves, 16 MFMA/K-step (m97 structure).
// MODE 0: C = A@Bt^T -> float out.
// MODE 1: fused QKV epilogue: cols<2048 -> per-head L2-normalize * mask ->
//         Qn/Kn [B*H,S,64]; cols>=2048 -> plain bf16 V to Vbuf [B*S,1024].
template<int MODE>
__global__ __launch_bounds__(256) void k_gemm128(const bf* __restrict__ A,
                                                 const bf* __restrict__ Bt,
                                                 float* __restrict__ Cf,
                                                 const int* __restrict__ masks,
                                                 bf* __restrict__ Qn,
                                                 bf* __restrict__ Kn,
                                                 bf* __restrict__ Vbuf,
                                                 int M, int N, int K) {
    __shared__ __align__(16) bf Asm[128 * 32];
    __shared__ __align__(16) bf Bsm[128 * 32];
    const int tid = threadIdx.x;
    const int w = tid >> 6, lane = tid & 63, g = lane >> 4, rl = lane & 15;
    const int m0 = blockIdx.y * 128, n0 = blockIdx.x * 128;
    const int wr = (w >> 1) * 64, wc = (w & 1) * 64;
    const int srow = lane >> 2, sseg = lane & 3;

    f32x4 acc[4][4] = {};
    const bf* Ap = A + (size_t)m0 * K;
    const bf* Bp = Bt + (size_t)n0 * K;

    for (int k0 = 0; k0 < K; k0 += 32) {
        __syncthreads();
#pragma unroll
        for (int u = 0; u < 2; ++u) {
            const int c = w * 2 + u;
            const int row = c * 16 + srow;
            glds16(Ap + (size_t)row * K + k0 + sseg * 8, &Asm[c * 512]);
            glds16(Bp + (size_t)row * K + k0 + sseg * 8, &Bsm[c * 512]);
        }
        __syncthreads();

        bf16x8 af[4], bfr[4];
#pragma unroll
        for (int m = 0; m < 4; ++m)
            af[m] = __builtin_bit_cast(bf16x8, *(const int4*)&Asm[(wr + m * 16 + rl) * 32 + g * 8]);
#pragma unroll
        for (int n = 0; n < 4; ++n)
            bfr[n] = __builtin_bit_cast(bf16x8, *(const int4*)&Bsm[(wc + n * 16 + rl) * 32 + g * 8]);
#pragma unroll
        for (int m = 0; m < 4; ++m)
#pragma unroll
            for (int n = 0; n < 4; ++n)
                acc[m][n] = mfma16(af[m], bfr[n], acc[m][n]);
    }

    if constexpr (MODE == 0) {
#pragma unroll
        for (int m = 0; m < 4; ++m)
#pragma unroll
            for (int n = 0; n < 4; ++n)
#pragma unroll
                for (int ri = 0; ri < 4; ++ri)
                    Cf[(size_t)(m0 + wr + m * 16 + g * 4 + ri) * N + n0 + wc + n * 16 + rl] =
                        acc[m][n][ri];
    } else {
        const int ncol0 = n0 + wc;   // wave's 64-col base == one head slice
#pragma unroll
        for (int m = 0; m < 4; ++m) {
#pragma unroll
            for (int ri = 0; ri < 4; ++ri) {
                const int row = m0 + wr + m * 16 + g * 4 + ri;   // b*S+s
                if (ncol0 < 2048) {
                    float ss = 0.f;
#pragma unroll
                    for (int n = 0; n < 4; ++n) ss += acc[m][n][ri] * acc[m][n][ri];
#pragma unroll
                    for (int d = 1; d < 16; d <<= 1) ss += __shfl_xor(ss, d, 64);
                    const float sc = rsqrtf(ss) * (masks[row] ? 1.0f : 0.0f);
                    bf* dst = (ncol0 < 1024) ? Qn : Kn;
                    const int h = (ncol0 >> 6) & 15;
                    const int b = row >> 11, s = row & 2047;
                    const size_t base = ((size_t)(b * HH + h) * SS + s) * 64;
#pragma unroll
                    for (int n = 0; n < 4; ++n)
                        dst[base + n * 16 + rl] = __float2bfloat16(acc[m][n][ri] * sc);
                } else {
                    const size_t base = (size_t)row * 1024 + (ncol0 - 2048);
#pragma unroll
                    for (int n = 0; n < 4; ++n)
                        Vbuf[base + n * 16 + rl] = __float2bfloat16(acc[m][n][ri]);
                }
            }
        }
    }
}

// ---------------------------------------------------------------
// V: Vbuf [B*S, 1024] -> Vt: [B*H, 64, S]
__global__ __launch_bounds__(256) void k_transpose_v(const bf* __restrict__ Vbuf,
                                                     bf* __restrict__ Vt) {
    __shared__ bf tile[64][65];
    const int by = blockIdx.y;            // b*H + h
    const int b = by >> 4, h = by & 15;
    const int s0 = blockIdx.x * 64;
    for (int i = threadIdx.x; i < 64 * 64; i += 256) {
        int sl = i >> 6, dl = i & 63;
        tile[dl][sl] = Vbuf[(size_t)(b * SS + s0 + sl) * DD + h * 64 + dl];
    }
    __syncthreads();
    for (int i = threadIdx.x; i < 64 * 64; i += 256) {
        int dl = i >> 6, sl = i & 63;
        Vt[((size_t)by * 64 + dl) * SS + s0 + sl] = tile[dl][sl];
    }
}

// ---------------------------------------------------------------
// Attention, 32x32 MFMA + in-register P (T12).
// 1D grid 512 (LPT: qt descending). Block = 4 waves; wave w owns q rows
// [qt*128 + w*32, +32). K/V (64 kv x 64 d) double-buffered in LDS, XOR-swizzled
// via pre-swizzled glds source. Swapped QK^T: P[k][q=lane&31] in f32x16 regs;
// cvt_pk + permlane32_swap builds PV A-fragments with zero LDS traffic.
__global__ __launch_bounds__(256) void k_attn(const bf* __restrict__ Qn,  // [B*H,S,64]
                                              const bf* __restrict__ Kn,  // [B*H,S,64]
                                              const bf* __restrict__ Vt,  // [B*H,64,S]
                                              bf* __restrict__ Ctx) {     // [B*S, D]
    __shared__ __align__(16) bf Ksm[2][64 * 64];  // [kv][d]
    __shared__ __align__(16) bf Vsm[2][64 * 64];  // [d][kv]

    const int idx = blockIdx.x;
    const int qt = 15 - (idx >> 5);       // largest-first (LPT)
    const int by = idx & 31;              // b*H + h
    const int b = by >> 4, h = by & 15;
    const int tid = threadIdx.x;
    const int w = tid >> 6, lane = tid & 63;
    const int l31 = lane & 31, hl = lane >> 5;
    const int qw = qt * 128 + w * 32;     // wave's first q row
    const int qg = qw + l31;              // lane's q column

    const bf* Qp = Qn + (size_t)by * SS * 64;
    const bf* Kp = Kn + (size_t)by * SS * 64;
    const bf* Vp = Vt + (size_t)by * 64 * SS;

    // hoisted Q (B-operand): col=q=l31, d = st*16 + hl*8 + 0..7
    bf16x8 aqs[4];
#pragma unroll
    for (int st = 0; st < 4; ++st)
        aqs[st] = __builtin_bit_cast(bf16x8,
            *(const int4*)(Qp + (size_t)(qw + l31) * 64 + st * 16 + hl * 8));

    // staging: chunk c = 8 rows x 128B; pre-swizzled source slot
    const int srow = lane >> 3;
    const int sblk = (lane & 7) ^ srow;

    auto stage = [&](int buf, int k0) {
#pragma unroll
        for (int u = 0; u < 2; ++u) {
            const int c = w * 2 + u;
            const int row = c * 8 + srow;
            glds16(Kp + (size_t)(k0 + row) * 64 + sblk * 8, &Ksm[buf][c * 512]);
            glds16(Vp + (size_t)row * SS + k0 + sblk * 8, &Vsm[buf][c * 512]);
        }
    };

    f32x16 accd[2] = {};
    const int tmax = 2 * qt + 1;

    stage(0, 0);
    __syncthreads();
    int cur = 0;
    for (int t = 0; t <= tmax; ++t) {
        if (t < tmax) stage(cur ^ 1, (t + 1) * 64);
#pragma unroll
        for (int pt = 0; pt < 2; ++pt) {
            const int kbase = t * 64 + pt * 32;
            if (kbase > qw + 31) continue;        // fully future-masked
            // ---- QK^T (swapped): D[row=k][col=q]
            f32x16 pc = {};
#pragma unroll
            for (int st = 0; st < 4; ++st) {
                const int r = pt * 32 + l31;
                bf16x8 ak = __builtin_bit_cast(bf16x8,
                    *(const int4*)&Ksm[cur][r * 64 + (((2 * st + hl) ^ (r & 7)) << 3)]);
                pc = mfma32(ak, aqs[st], pc);
            }
            // ---- relu + causal (elementwise only near diagonal)
            const bool dg = (kbase + 31 > qw);
            float pv[16];
#pragma unroll
            for (int m2 = 0; m2 < 16; ++m2) {
                float v = fmaxf(pc[m2], 0.0f);
                if (dg) {
                    const int kg = kbase + (m2 & 3) + 8 * (m2 >> 2) + 4 * hl;
                    if (kg > qg) v = 0.0f;
                }
                pv[m2] = v;
            }
            // ---- pack to bf16 pairs + permlane swaps -> PV A-frags (no LDS)
            unsigned P[8];
#pragma unroll
            for (int m2 = 0; m2 < 8; ++m2) P[m2] = cvt_pk_bf16(pv[2 * m2], pv[2 * m2 + 1]);
            pl32swap(P[0], P[2]);
            pl32swap(P[1], P[3]);
            pl32swap(P[4], P[6]);
            pl32swap(P[5], P[7]);
            // ---- PV: D[row=q][col=d]
#pragma unroll
            for (int s = 0; s < 2; ++s) {
                uint4 pw = {P[4 * s + 0], P[4 * s + 1], P[4 * s + 2], P[4 * s + 3]};
                bf16x8 pa = __builtin_bit_cast(bf16x8, pw);
#pragma unroll
                for (int dt = 0; dt < 2; ++dt) {
                    const int d = dt * 32 + l31;
                    const int slot = pt * 4 + s * 2 + hl;
                    bf16x8 bv = __builtin_bit_cast(bf16x8,
                        *(const int4*)&Vsm[cur][d * 64 + ((slot ^ (d & 7)) << 3)]);
                    accd[dt] = mfma32(pa, bv, accd[dt]);
                }
            }
        }
        __syncthreads();
        cur ^= 1;
    }

    // epilogue: Ctx[b*S+q][h*64+d]
#pragma unroll
    for (int dt = 0; dt < 2; ++dt)
#pragma unroll
        for (int m2 = 0; m2 < 16; ++m2) {
            const int q = qw + (m2 & 3) + 8 * (m2 >> 2) + 4 * hl;
            const int d = dt * 32 + l31;
            Ctx[(size_t)(b * SS + q) * DD + h * 64 + d] = __float2bfloat16(accd[dt][m2]);
        }
}

// ---------------------------------------------------------------
extern "C" void kernel_launch(void* const* d_in, const int* in_sizes, int n_in,
                              void* d_out, int out_size, void* d_ws, size_t ws_size,
                              hipStream_t stream) {
    const float* X  = (const float*)d_in[0];
    const int* masks = (const int*)d_in[1];
    const float* Wq = (const float*)d_in[2];
    const float* Wk = (const float*)d_in[3];
    const float* Wv = (const float*)d_in[4];
    const float* Wo = (const float*)d_in[5];
    float* out = (float*)d_out;
    char* ws = (char*)d_ws;

    const size_t MB = 1024 * 1024;
    bf* Xb   = (bf*)(ws);              // 8 MB  [B*S, D]
    bf* Wqkv = (bf*)(ws + 8  * MB);    // 6 MB  [3072, 1024]
    bf* Wob  = (bf*)(ws + 14 * MB);    // 2 MB
    bf* Qn   = (bf*)(ws + 16 * MB);    // 8 MB  [B*H, S, 64]
    bf* Kn   = (bf*)(ws + 24 * MB);
    bf* Vbuf = (bf*)(ws + 32 * MB);    // 8 MB  [B*S, 1024]
    bf* Vt   = (bf*)(ws + 40 * MB);    // 8 MB  [B*H, 64, S]
    bf* Ctx  = (bf*)(ws + 48 * MB);    // 8 MB  [B*S, D]

    // converts
    k_f32_to_bf16<<<MMR * DD / 1024, 256, 0, stream>>>(X, Xb);
    k_conv_w<<<4096, 256, 0, stream>>>(Wq, Wk, Wv, Wo, Wqkv, Wob);

    // fused QKV projection + norm/mask epilogue
    k_gemm128<1><<<dim3(ND3 / 128, MMR / 128), 256, 0, stream>>>(
        Xb, Wqkv, nullptr, masks, Qn, Kn, Vbuf, MMR, ND3, DD);

    // V transpose
    k_transpose_v<<<dim3(SS / 64, BB * HH), 256, 0, stream>>>(Vbuf, Vt);

    // attention
    k_attn<<<512, 256, 0, stream>>>(Qn, Kn, Vt, Ctx);

    // output projection
    k_gemm128<0><<<dim3(DD / 128, MMR / 128), 256, 0, stream>>>(
        Ctx, Wob, out, nullptr, nullptr, nullptr, nullptr, MMR, DD, DD);
}

// Round 4
// 127.699 us; speedup vs baseline: 2.8036x; 1.1175x over previous
//
#include <hip/hip_runtime.h>
#include <hip/hip_bf16.h>

// Problem constants
#define BB 2
#define SS 2048
#define DD 1024
#define HH 16
#define MMR (BB*SS)   // 4096 rows
#define ND3 3072      // fused QKV width

typedef __hip_bfloat16 bf;
typedef __bf16 bf16x8 __attribute__((ext_vector_type(8)));
typedef float f32x4 __attribute__((ext_vector_type(4)));
typedef float f32x16 __attribute__((ext_vector_type(16)));

__device__ __forceinline__ f32x4 mfma16(bf16x8 a, bf16x8 b, f32x4 c) {
    return __builtin_amdgcn_mfma_f32_16x16x32_bf16(a, b, c, 0, 0, 0);
}
__device__ __forceinline__ f32x16 mfma32(bf16x8 a, bf16x8 b, f32x16 c) {
    return __builtin_amdgcn_mfma_f32_32x32x16_bf16(a, b, c, 0, 0, 0);
}
__device__ __forceinline__ unsigned cvt_pk_bf16(float lo, float hi) {
    unsigned r;
    asm("v_cvt_pk_bf16_f32 %0, %1, %2" : "=v"(r) : "v"(lo), "v"(hi));
    return r;
}
// after: a = {a.lo31, b.lo31}, b = {a.hi31, b.hi31}
__device__ __forceinline__ void pl32swap(unsigned& a, unsigned& b) {
    asm("v_permlane32_swap_b32 %0, %1" : "+v"(a), "+v"(b));
}
// async global->LDS, 16B/lane; LDS dest = wave-uniform base + lane*16
__device__ __forceinline__ void glds16(const bf* g, bf* l) {
    __builtin_amdgcn_global_load_lds(
        (const __attribute__((address_space(1))) void*)g,
        (__attribute__((address_space(3))) void*)l,
        16, 0, 0);
}

// ---------------------------------------------------------------
// f32 -> bf16, 4 elems/thread, 1024 elems/block
__global__ __launch_bounds__(256) void k_f32_to_bf16(const float* __restrict__ src,
                                                     bf* __restrict__ dst) {
    int j = (blockIdx.x * 256 + threadIdx.x) * 4;
    float4 v = *(const float4*)(src + j);
    bf tmp[4];
    tmp[0] = __float2bfloat16(v.x);
    tmp[1] = __float2bfloat16(v.y);
    tmp[2] = __float2bfloat16(v.z);
    tmp[3] = __float2bfloat16(v.w);
    *(uint2*)(dst + j) = *(const uint2*)tmp;
}

// 4 weight matrices (1M elems each) in one launch: region = blockIdx.x>>10
__global__ __launch_bounds__(256) void k_conv_w(const float* __restrict__ Wq,
                                                const float* __restrict__ Wk,
                                                const float* __restrict__ Wv,
                                                const float* __restrict__ Wo,
                                                bf* __restrict__ Wqkv,
                                                bf* __restrict__ Wob) {
    const int r = blockIdx.x >> 10;
    const float* src = (r == 0) ? Wq : (r == 1) ? Wk : (r == 2) ? Wv : Wo;
    bf* dst = (r < 3) ? (Wqkv + (size_t)r * 1048576) : Wob;
    int j = (((blockIdx.x & 1023) * 256) + threadIdx.x) * 4;
    float4 v = *(const float4*)(src + j);
    bf tmp[4];
    tmp[0] = __float2bfloat16(v.x);
    tmp[1] = __float2bfloat16(v.y);
    tmp[2] = __float2bfloat16(v.z);
    tmp[3] = __float2bfloat16(v.w);
    *(uint2*)(dst + j) = *(const uint2*)tmp;
}

// ---------------------------------------------------------------
// 128x128-tile GEMM, BK=32, 4 waves, 16 MFMA/K-step (m97 structure).
// 1D grid with XCD-chunked swizzle (nwg % 8 == 0).
// MODE 0: C = A@Bt^T -> float out.
// MODE 1: fused QKV epilogue: cols<2048 -> per-head L2-normalize * mask ->
//         Qn/Kn [B*H,S,64]; cols>=2048 -> plain bf16 V to Vbuf [B*S,1024].
template<int MODE>
__global__ __launch_bounds__(256) void k_gemm128(const bf* __restrict__ A,
                                                 const bf* __restrict__ Bt,
                                                 float* __restrict__ Cf,
                                                 const int* __restrict__ masks,
                                                 bf* __restrict__ Qn,
                                                 bf* __restrict__ Kn,
                                                 bf* __restrict__ Vbuf,
                                                 int nx, int M, int N, int K) {
    __shared__ __align__(16) bf Asm[128 * 32];
    __shared__ __align__(16) bf Bsm[128 * 32];
    const int tid = threadIdx.x;
    const int w = tid >> 6, lane = tid & 63, g = lane >> 4, rl = lane & 15;
    // XCD-chunked bijective swizzle (T1): xcd = orig % 8
    const int cpx = gridDim.x >> 3;
    const int swz = (blockIdx.x & 7) * cpx + (blockIdx.x >> 3);
    const int m0 = (swz / nx) * 128, n0 = (swz % nx) * 128;
    const int wr = (w >> 1) * 64, wc = (w & 1) * 64;
    const int srow = lane >> 2, sseg = lane & 3;

    f32x4 acc[4][4] = {};
    const bf* Ap = A + (size_t)m0 * K;
    const bf* Bp = Bt + (size_t)n0 * K;

    for (int k0 = 0; k0 < K; k0 += 32) {
        __syncthreads();
#pragma unroll
        for (int u = 0; u < 2; ++u) {
            const int c = w * 2 + u;
            const int row = c * 16 + srow;
            glds16(Ap + (size_t)row * K + k0 + sseg * 8, &Asm[c * 512]);
            glds16(Bp + (size_t)row * K + k0 + sseg * 8, &Bsm[c * 512]);
        }
        __syncthreads();

        bf16x8 af[4], bfr[4];
#pragma unroll
        for (int m = 0; m < 4; ++m)
            af[m] = __builtin_bit_cast(bf16x8, *(const int4*)&Asm[(wr + m * 16 + rl) * 32 + g * 8]);
#pragma unroll
        for (int n = 0; n < 4; ++n)
            bfr[n] = __builtin_bit_cast(bf16x8, *(const int4*)&Bsm[(wc + n * 16 + rl) * 32 + g * 8]);
#pragma unroll
        for (int m = 0; m < 4; ++m)
#pragma unroll
            for (int n = 0; n < 4; ++n)
                acc[m][n] = mfma16(af[m], bfr[n], acc[m][n]);
    }

    if constexpr (MODE == 0) {
#pragma unroll
        for (int m = 0; m < 4; ++m)
#pragma unroll
            for (int n = 0; n < 4; ++n)
#pragma unroll
                for (int ri = 0; ri < 4; ++ri)
                    Cf[(size_t)(m0 + wr + m * 16 + g * 4 + ri) * N + n0 + wc + n * 16 + rl] =
                        acc[m][n][ri];
    } else {
        const int ncol0 = n0 + wc;   // wave's 64-col base == one head slice
#pragma unroll
        for (int m = 0; m < 4; ++m) {
#pragma unroll
            for (int ri = 0; ri < 4; ++ri) {
                const int row = m0 + wr + m * 16 + g * 4 + ri;   // b*S+s
                if (ncol0 < 2048) {
                    float ss = 0.f;
#pragma unroll
                    for (int n = 0; n < 4; ++n) ss += acc[m][n][ri] * acc[m][n][ri];
#pragma unroll
                    for (int d = 1; d < 16; d <<= 1) ss += __shfl_xor(ss, d, 64);
                    const float sc = rsqrtf(ss) * (masks[row] ? 1.0f : 0.0f);
                    bf* dst = (ncol0 < 1024) ? Qn : Kn;
                    const int h = (ncol0 >> 6) & 15;
                    const int b = row >> 11, s = row & 2047;
                    const size_t base = ((size_t)(b * HH + h) * SS + s) * 64;
#pragma unroll
                    for (int n = 0; n < 4; ++n)
                        dst[base + n * 16 + rl] = __float2bfloat16(acc[m][n][ri] * sc);
                } else {
                    const size_t base = (size_t)row * 1024 + (ncol0 - 2048);
#pragma unroll
                    for (int n = 0; n < 4; ++n)
                        Vbuf[base + n * 16 + rl] = __float2bfloat16(acc[m][n][ri]);
                }
            }
        }
    }
}

// ---------------------------------------------------------------
// V: Vbuf [B*S, 1024] -> Vt: [B*H, 64, S]
__global__ __launch_bounds__(256) void k_transpose_v(const bf* __restrict__ Vbuf,
                                                     bf* __restrict__ Vt) {
    __shared__ bf tile[64][65];
    const int by = blockIdx.y;            // b*H + h
    const int b = by >> 4, h = by & 15;
    const int s0 = blockIdx.x * 64;
    for (int i = threadIdx.x; i < 64 * 64; i += 256) {
        int sl = i >> 6, dl = i & 63;
        tile[dl][sl] = Vbuf[(size_t)(b * SS + s0 + sl) * DD + h * 64 + dl];
    }
    __syncthreads();
    for (int i = threadIdx.x; i < 64 * 64; i += 256) {
        int dl = i >> 6, sl = i & 63;
        Vt[((size_t)by * 64 + dl) * SS + s0 + sl] = tile[dl][sl];
    }
}

// ---------------------------------------------------------------
// Attention, 32x32 MFMA + in-register P (T12), q-tile 64, 1024 blocks (LPT).
// 4 waves = (q-half qh) x (k-parity kp): wave computes only k-subtiles pt==kp
// -> per-wave LDS reads halve; partial O's summed via one-time LDS reduce
// (valid because relu-attention has no softmax: O = sum_k P[q,k] V[k]).
__global__ __launch_bounds__(256) void k_attn(const bf* __restrict__ Qn,  // [B*H,S,64]
                                              const bf* __restrict__ Kn,  // [B*H,S,64]
                                              const bf* __restrict__ Vt,  // [B*H,64,S]
                                              bf* __restrict__ Ctx) {     // [B*S, D]
    __shared__ __align__(16) bf Ksm[2][64 * 64];  // [kv][d], 16KB
    __shared__ __align__(16) bf Vsm[2][64 * 64];  // [d][kv], 16KB

    const int idx = blockIdx.x;
    const int qt = 31 - (idx >> 5);       // 0..31, largest-first (LPT)
    const int by = idx & 31;              // b*H + h
    const int b = by >> 4, h = by & 15;
    const int tid = threadIdx.x;
    const int w = tid >> 6, lane = tid & 63;
    const int l31 = lane & 31, hl = lane >> 5;
    const int qh = w >> 1;                // q-half: rows qt*64+qh*32 ..+32
    const int kp = w & 1;                 // k-parity: handles pt == kp
    const int qw = qt * 64 + qh * 32;
    const int qg = qw + l31;

    const bf* Qp = Qn + (size_t)by * SS * 64;
    const bf* Kp = Kn + (size_t)by * SS * 64;
    const bf* Vp = Vt + (size_t)by * 64 * SS;

    // hoisted Q (B-operand): col=q=l31, d = st*16 + hl*8 + 0..7
    bf16x8 aqs[4];
#pragma unroll
    for (int st = 0; st < 4; ++st)
        aqs[st] = __builtin_bit_cast(bf16x8,
            *(const int4*)(Qp + (size_t)(qw + l31) * 64 + st * 16 + hl * 8));

    // staging: chunk c = 8 rows x 128B; pre-swizzled source slot
    const int srow = lane >> 3;
    const int sblk = (lane & 7) ^ srow;

    auto stage = [&](int buf, int k0) {
#pragma unroll
        for (int u = 0; u < 2; ++u) {
            const int c = w * 2 + u;
            const int row = c * 8 + srow;
            glds16(Kp + (size_t)(k0 + row) * 64 + sblk * 8, &Ksm[buf][c * 512]);
            glds16(Vp + (size_t)row * SS + k0 + sblk * 8, &Vsm[buf][c * 512]);
        }
    };

    f32x16 accd[2] = {};

    stage(0, 0);
    __syncthreads();
    int cur = 0;
    for (int t = 0; t <= qt; ++t) {
        if (t < qt) stage(cur ^ 1, (t + 1) * 64);
        const int kbase = t * 64 + kp * 32;
        if (kbase <= qw + 31) {
            // ---- QK^T (swapped): D[row=k][col=q]
            f32x16 pc = {};
#pragma unroll
            for (int st = 0; st < 4; ++st) {
                const int r = kp * 32 + l31;
                bf16x8 ak = __builtin_bit_cast(bf16x8,
                    *(const int4*)&Ksm[cur][r * 64 + (((2 * st + hl) ^ (r & 7)) << 3)]);
                pc = mfma32(ak, aqs[st], pc);
            }
            // ---- relu + causal (elementwise only near diagonal)
            const bool dg = (kbase + 31 > qw);
            float pv[16];
#pragma unroll
            for (int m2 = 0; m2 < 16; ++m2) {
                float v = fmaxf(pc[m2], 0.0f);
                if (dg) {
                    const int kg = kbase + (m2 & 3) + 8 * (m2 >> 2) + 4 * hl;
                    if (kg > qg) v = 0.0f;
                }
                pv[m2] = v;
            }
            // ---- pack to bf16 pairs + permlane swaps -> PV A-frags (no LDS)
            unsigned P[8];
#pragma unroll
            for (int m2 = 0; m2 < 8; ++m2) P[m2] = cvt_pk_bf16(pv[2 * m2], pv[2 * m2 + 1]);
            pl32swap(P[0], P[2]);
            pl32swap(P[1], P[3]);
            pl32swap(P[4], P[6]);
            pl32swap(P[5], P[7]);
            // ---- PV: D[row=q][col=d]
#pragma unroll
            for (int s = 0; s < 2; ++s) {
                uint4 pw = {P[4 * s + 0], P[4 * s + 1], P[4 * s + 2], P[4 * s + 3]};
                bf16x8 pa = __builtin_bit_cast(bf16x8, pw);
#pragma unroll
                for (int dt = 0; dt < 2; ++dt) {
                    const int d = dt * 32 + l31;
                    const int slot = kp * 4 + s * 2 + hl;
                    bf16x8 bv = __builtin_bit_cast(bf16x8,
                        *(const int4*)&Vsm[cur][d * 64 + ((slot ^ (d & 7)) << 3)]);
                    accd[dt] = mfma32(pa, bv, accd[dt]);
                }
            }
        }
        __syncthreads();
        cur ^= 1;
    }

    // ---- cross-wave (k-parity) reduce via LDS, then kp==0 writes Ctx
    float* red = (float*)&Ksm[0][0];      // 16KB: 2 q-halves x 8KB
    if (kp == 1) {
#pragma unroll
        for (int dt = 0; dt < 2; ++dt)
#pragma unroll
            for (int m2 = 0; m2 < 16; ++m2)
                red[qh * 2048 + (dt * 16 + m2) * 64 + lane] = accd[dt][m2];
    }
    __syncthreads();
    if (kp == 0) {
#pragma unroll
        for (int dt = 0; dt < 2; ++dt)
#pragma unroll
            for (int m2 = 0; m2 < 16; ++m2) {
                const float v = accd[dt][m2] + red[qh * 2048 + (dt * 16 + m2) * 64 + lane];
                const int q = qw + (m2 & 3) + 8 * (m2 >> 2) + 4 * hl;
                const int d = dt * 32 + l31;
                Ctx[(size_t)(b * SS + q) * DD + h * 64 + d] = __float2bfloat16(v);
            }
    }
}

// ---------------------------------------------------------------
extern "C" void kernel_launch(void* const* d_in, const int* in_sizes, int n_in,
                              void* d_out, int out_size, void* d_ws, size_t ws_size,
                              hipStream_t stream) {
    const float* X  = (const float*)d_in[0];
    const int* masks = (const int*)d_in[1];
    const float* Wq = (const float*)d_in[2];
    const float* Wk = (const float*)d_in[3];
    const float* Wv = (const float*)d_in[4];
    const float* Wo = (const float*)d_in[5];
    float* out = (float*)d_out;
    char* ws = (char*)d_ws;

    const size_t MB = 1024 * 1024;
    bf* Xb   = (bf*)(ws);              // 8 MB  [B*S, D]
    bf* Wqkv = (bf*)(ws + 8  * MB);    // 6 MB  [3072, 1024]
    bf* Wob  = (bf*)(ws + 14 * MB);    // 2 MB
    bf* Qn   = (bf*)(ws + 16 * MB);    // 8 MB  [B*H, S, 64]
    bf* Kn   = (bf*)(ws + 24 * MB);
    bf* Vbuf = (bf*)(ws + 32 * MB);    // 8 MB  [B*S, 1024]
    bf* Vt   = (bf*)(ws + 40 * MB);    // 8 MB  [B*H, 64, S]
    bf* Ctx  = (bf*)(ws + 48 * MB);    // 8 MB  [B*S, D]

    // converts
    k_f32_to_bf16<<<MMR * DD / 1024, 256, 0, stream>>>(X, Xb);
    k_conv_w<<<4096, 256, 0, stream>>>(Wq, Wk, Wv, Wo, Wqkv, Wob);

    // fused QKV projection + norm/mask epilogue (768 blocks, %8==0)
    k_gemm128<1><<<(ND3 / 128) * (MMR / 128), 256, 0, stream>>>(
        Xb, Wqkv, nullptr, masks, Qn, Kn, Vbuf, ND3 / 128, MMR, ND3, DD);

    // V transpose
    k_transpose_v<<<dim3(SS / 64, BB * HH), 256, 0, stream>>>(Vbuf, Vt);

    // attention
    k_attn<<<1024, 256, 0, stream>>>(Qn, Kn, Vt, Ctx);

    // output projection (256 blocks, %8==0)
    k_gemm128<0><<<(DD / 128) * (MMR / 128), 256, 0, stream>>>(
        Ctx, Wob, out, nullptr, nullptr, nullptr, nullptr, DD / 128, MMR, DD, DD);
}

// Round 5
// 102.487 us; speedup vs baseline: 3.4933x; 1.2460x over previous
//
#include <hip/hip_runtime.h>
#include <hip/hip_bf16.h>

// Problem constants
#define BB 2
#define SS 2048
#define DD 1024
#define HH 16
#define MMR (BB*SS)   // 4096 rows
#define ND3 3072      // fused QKV width

typedef __hip_bfloat16 bf;
typedef __bf16 bf16x8 __attribute__((ext_vector_type(8)));
typedef float f32x4 __attribute__((ext_vector_type(4)));
typedef float f32x16 __attribute__((ext_vector_type(16)));

#define VMCNT(n) asm volatile("s_waitcnt vmcnt(" #n ")" ::: "memory")

__device__ __forceinline__ f32x4 mfma16(bf16x8 a, bf16x8 b, f32x4 c) {
    return __builtin_amdgcn_mfma_f32_16x16x32_bf16(a, b, c, 0, 0, 0);
}
__device__ __forceinline__ f32x16 mfma32(bf16x8 a, bf16x8 b, f32x16 c) {
    return __builtin_amdgcn_mfma_f32_32x32x16_bf16(a, b, c, 0, 0, 0);
}
__device__ __forceinline__ unsigned cvt_pk_bf16(float lo, float hi) {
    unsigned r;
    asm("v_cvt_pk_bf16_f32 %0, %1, %2" : "=v"(r) : "v"(lo), "v"(hi));
    return r;
}
// after: a = {a.lo31, b.lo31}, b = {a.hi31, b.hi31}
__device__ __forceinline__ void pl32swap(unsigned& a, unsigned& b) {
    asm("v_permlane32_swap_b32 %0, %1" : "+v"(a), "+v"(b));
}
// async global->LDS, 16B/lane; LDS dest = wave-uniform base + lane*16
__device__ __forceinline__ void glds16(const bf* g, bf* l) {
    __builtin_amdgcn_global_load_lds(
        (const __attribute__((address_space(1))) void*)g,
        (__attribute__((address_space(3))) void*)l,
        16, 0, 0);
}

// ---------------------------------------------------------------
// All f32->bf16 converts in ONE launch. blocks 0..4095: X (4M elems);
// blocks 4096..8191: Wq,Wk,Wv (into Wqkv) and Wo (into Wob), 1M each.
__global__ __launch_bounds__(256) void k_convert(const float* __restrict__ X,
                                                 const float* __restrict__ Wq,
                                                 const float* __restrict__ Wk,
                                                 const float* __restrict__ Wv,
                                                 const float* __restrict__ Wo,
                                                 bf* __restrict__ Xb,
                                                 bf* __restrict__ Wqkv,
                                                 bf* __restrict__ Wob) {
    const int bid = blockIdx.x;
    const float* src;
    bf* dst;
    int off;
    if (bid < 4096) {
        src = X; dst = Xb; off = bid;
    } else {
        const int r = (bid - 4096) >> 10;
        src = (r == 0) ? Wq : (r == 1) ? Wk : (r == 2) ? Wv : Wo;
        dst = (r < 3) ? (Wqkv + (size_t)r * 1048576) : Wob;
        off = (bid - 4096) & 1023;
    }
    const int j = (off * 256 + threadIdx.x) * 4;
    float4 v = *(const float4*)(src + j);
    bf tmp[4];
    tmp[0] = __float2bfloat16(v.x);
    tmp[1] = __float2bfloat16(v.y);
    tmp[2] = __float2bfloat16(v.z);
    tmp[3] = __float2bfloat16(v.w);
    *(uint2*)(dst + j) = *(const uint2*)tmp;
}

// ---------------------------------------------------------------
// BMxBN-tile GEMM, BK=32, 4 waves. 3-buffer LDS pipeline with counted vmcnt
// (loads stay in flight across the raw s_barrier; one barrier per K-step).
// MODE 0: C = A@Bt^T -> float out.
// MODE 1 (BM=128): fused QKV epilogue: cols<2048 -> per-head L2-norm * mask ->
//   Qn/Kn [B*H,S,64]; cols>=2048 -> TRANSPOSED bf16 write to Vt [B*H,64,S].
template<int MODE, int BM, int BN>
__global__ __launch_bounds__(256) void k_gemm(const bf* __restrict__ A,
                                              const bf* __restrict__ Bt,
                                              float* __restrict__ Cf,
                                              const int* __restrict__ masks,
                                              bf* __restrict__ Qn,
                                              bf* __restrict__ Kn,
                                              bf* __restrict__ Vt,
                                              int nx, int N, int K) {
    constexpr int MF = BM / 32;          // M fragments per wave
    constexpr int RA = BM / 64;          // A staging rounds (glds16/thread)
    constexpr int RB = BN / 64;
    __shared__ __align__(16) bf Asm[3][BM * 32];
    __shared__ __align__(16) bf Bsm[3][BN * 32];
    const int tid = threadIdx.x;
    const int w = tid >> 6, lane = tid & 63, g = lane >> 4, rl = lane & 15;
    // XCD-chunked bijective swizzle (T1): gridDim.x % 8 == 0
    const int cpx = gridDim.x >> 3;
    const int swz = (blockIdx.x & 7) * cpx + (blockIdx.x >> 3);
    const int m0 = (swz / nx) * BM, n0 = (swz % nx) * BN;
    const int wr = (w >> 1) * (MF * 16), wc = (w & 1) * 64;
    const int lrow = lane >> 2, lseg = lane & 3;

    f32x4 acc[MF][4] = {};
    const bf* Ap = A + (size_t)m0 * K;
    const bf* Bp = Bt + (size_t)n0 * K;

    auto stage = [&](int bi, int k0) {
#pragma unroll
        for (int u = 0; u < RA; ++u)
            glds16(Ap + (size_t)(u * 64 + w * 16 + lrow) * K + k0 + lseg * 8,
                   &Asm[bi][(u * 64 + w * 16) * 32]);
#pragma unroll
        for (int u = 0; u < RB; ++u)
            glds16(Bp + (size_t)(u * 64 + w * 16 + lrow) * K + k0 + lseg * 8,
                   &Bsm[bi][(u * 64 + w * 16) * 32]);
    };

    const int T = K >> 5;
    stage(0, 0);
    stage(1, 32);
    int cur = 0, nxt = 2;
    for (int t = 0; t < T; ++t) {
        __builtin_amdgcn_sched_barrier(0);
        if (t < T - 1) {
            if constexpr (RA + RB == 4) VMCNT(4); else VMCNT(3);
        } else {
            VMCNT(0);
        }
        __builtin_amdgcn_s_barrier();     // raw: staged loads stay in flight
        __builtin_amdgcn_sched_barrier(0);
        if (t + 2 < T) stage(nxt, (t + 2) * 32);

        const bf* Ab = Asm[cur];
        const bf* Bb = Bsm[cur];
        bf16x8 af[MF], bfr[4];
#pragma unroll
        for (int m = 0; m < MF; ++m)
            af[m] = __builtin_bit_cast(bf16x8, *(const int4*)&Ab[(wr + m * 16 + rl) * 32 + g * 8]);
#pragma unroll
        for (int n = 0; n < 4; ++n)
            bfr[n] = __builtin_bit_cast(bf16x8, *(const int4*)&Bb[(wc + n * 16 + rl) * 32 + g * 8]);
#pragma unroll
        for (int m = 0; m < MF; ++m)
#pragma unroll
            for (int n = 0; n < 4; ++n)
                acc[m][n] = mfma16(af[m], bfr[n], acc[m][n]);

        cur = (cur == 2) ? 0 : cur + 1;
        nxt = (nxt == 2) ? 0 : nxt + 1;
    }

    if constexpr (MODE == 0) {
#pragma unroll
        for (int m = 0; m < MF; ++m)
#pragma unroll
            for (int n = 0; n < 4; ++n)
#pragma unroll
                for (int ri = 0; ri < 4; ++ri)
                    Cf[(size_t)(m0 + wr + m * 16 + g * 4 + ri) * N + n0 + wc + n * 16 + rl] =
                        acc[m][n][ri];
    } else {
        const int ncol0 = n0 + wc;   // wave's 64-col base == one head slice
        if (ncol0 < 2048) {
            bf* dst = (ncol0 < 1024) ? Qn : Kn;
            const int h2 = (ncol0 >> 6) & 15;
#pragma unroll
            for (int m = 0; m < MF; ++m) {
#pragma unroll
                for (int ri = 0; ri < 4; ++ri) {
                    const int row = m0 + wr + m * 16 + g * 4 + ri;   // b*S+s
                    float ss = 0.f;
#pragma unroll
                    for (int n = 0; n < 4; ++n) ss += acc[m][n][ri] * acc[m][n][ri];
#pragma unroll
                    for (int d = 1; d < 16; d <<= 1) ss += __shfl_xor(ss, d, 64);
                    const float sc = rsqrtf(ss) * (masks[row] ? 1.0f : 0.0f);
                    const int b = row >> 11, s = row & 2047;
                    const size_t base = ((size_t)(b * HH + h2) * SS + s) * 64;
#pragma unroll
                    for (int n = 0; n < 4; ++n)
                        dst[base + n * 16 + rl] = __float2bfloat16(acc[m][n][ri] * sc);
                }
            }
        } else {
            // fused V transpose: Vt[(b*H+h)*64 + d][s], packed 4-bf16 writes
            const int h2 = (ncol0 - 2048) >> 6;
            const int b = (m0 + wr) >> 11;
            const int sb = ((m0 + wr) & 2047) + g * 4;
#pragma unroll
            for (int m = 0; m < MF; ++m)
#pragma unroll
                for (int n = 0; n < 4; ++n) {
                    const int d = n * 16 + rl;
                    bf t4[4];
#pragma unroll
                    for (int ri = 0; ri < 4; ++ri) t4[ri] = __float2bfloat16(acc[m][n][ri]);
                    *(uint2*)&Vt[((size_t)(b * HH + h2) * 64 + d) * SS + sb + m * 16] =
                        *(uint2*)t4;
                }
        }
    }
}

// ---------------------------------------------------------------
// Attention, 32x32 MFMA + in-register P (T12), q-tile 64, 1024 blocks (LPT).
// 4 waves = (q-half qh) x (k-parity kp): wave computes only k-subtiles pt==kp
// -> per-wave LDS reads halve; partial O's summed via one-time LDS reduce
// (valid because relu-attention has no softmax: O = sum_k P[q,k] V[k]).
__global__ __launch_bounds__(256) void k_attn(const bf* __restrict__ Qn,  // [B*H,S,64]
                                              const bf* __restrict__ Kn,  // [B*H,S,64]
                                              const bf* __restrict__ Vt,  // [B*H,64,S]
                                              bf* __restrict__ Ctx) {     // [B*S, D]
    __shared__ __align__(16) bf Ksm[2][64 * 64];  // [kv][d], 16KB
    __shared__ __align__(16) bf Vsm[2][64 * 64];  // [d][kv], 16KB

    const int idx = blockIdx.x;
    const int qt = 31 - (idx >> 5);       // 0..31, largest-first (LPT)
    const int by = idx & 31;              // b*H + h
    const int b = by >> 4, h = by & 15;
    const int tid = threadIdx.x;
    const int w = tid >> 6, lane = tid & 63;
    const int l31 = lane & 31, hl = lane >> 5;
    const int qh = w >> 1;                // q-half: rows qt*64+qh*32 ..+32
    const int kp = w & 1;                 // k-parity: handles pt == kp
    const int qw = qt * 64 + qh * 32;
    const int qg = qw + l31;

    const bf* Qp = Qn + (size_t)by * SS * 64;
    const bf* Kp = Kn + (size_t)by * SS * 64;
    const bf* Vp = Vt + (size_t)by * 64 * SS;

    // hoisted Q (B-operand): col=q=l31, d = st*16 + hl*8 + 0..7
    bf16x8 aqs[4];
#pragma unroll
    for (int st = 0; st < 4; ++st)
        aqs[st] = __builtin_bit_cast(bf16x8,
            *(const int4*)(Qp + (size_t)(qw + l31) * 64 + st * 16 + hl * 8));

    // staging: chunk c = 8 rows x 128B; pre-swizzled source slot
    const int srow = lane >> 3;
    const int sblk = (lane & 7) ^ srow;

    auto stage = [&](int buf, int k0) {
#pragma unroll
        for (int u = 0; u < 2; ++u) {
            const int c = w * 2 + u;
            const int row = c * 8 + srow;
            glds16(Kp + (size_t)(k0 + row) * 64 + sblk * 8, &Ksm[buf][c * 512]);
            glds16(Vp + (size_t)row * SS + k0 + sblk * 8, &Vsm[buf][c * 512]);
        }
    };

    f32x16 accd[2] = {};

    stage(0, 0);
    __syncthreads();
    int cur = 0;
    for (int t = 0; t <= qt; ++t) {
        if (t < qt) stage(cur ^ 1, (t + 1) * 64);
        const int kbase = t * 64 + kp * 32;
        if (kbase <= qw + 31) {
            // ---- QK^T (swapped): D[row=k][col=q]
            f32x16 pc = {};
#pragma unroll
            for (int st = 0; st < 4; ++st) {
                const int r = kp * 32 + l31;
                bf16x8 ak = __builtin_bit_cast(bf16x8,
                    *(const int4*)&Ksm[cur][r * 64 + (((2 * st + hl) ^ (r & 7)) << 3)]);
                pc = mfma32(ak, aqs[st], pc);
            }
            // ---- relu + causal (elementwise only near diagonal)
            const bool dg = (kbase + 31 > qw);
            float pv[16];
#pragma unroll
            for (int m2 = 0; m2 < 16; ++m2) {
                float v = fmaxf(pc[m2], 0.0f);
                if (dg) {
                    const int kg = kbase + (m2 & 3) + 8 * (m2 >> 2) + 4 * hl;
                    if (kg > qg) v = 0.0f;
                }
                pv[m2] = v;
            }
            // ---- pack to bf16 pairs + permlane swaps -> PV A-frags (no LDS)
            unsigned P[8];
#pragma unroll
            for (int m2 = 0; m2 < 8; ++m2) P[m2] = cvt_pk_bf16(pv[2 * m2], pv[2 * m2 + 1]);
            pl32swap(P[0], P[2]);
            pl32swap(P[1], P[3]);
            pl32swap(P[4], P[6]);
            pl32swap(P[5], P[7]);
            // ---- PV: D[row=q][col=d]
#pragma unroll
            for (int s = 0; s < 2; ++s) {
                uint4 pw = {P[4 * s + 0], P[4 * s + 1], P[4 * s + 2], P[4 * s + 3]};
                bf16x8 pa = __builtin_bit_cast(bf16x8, pw);
#pragma unroll
                for (int dt = 0; dt < 2; ++dt) {
                    const int d = dt * 32 + l31;
                    const int slot = kp * 4 + s * 2 + hl;
                    bf16x8 bv = __builtin_bit_cast(bf16x8,
                        *(const int4*)&Vsm[cur][d * 64 + ((slot ^ (d & 7)) << 3)]);
                    accd[dt] = mfma32(pa, bv, accd[dt]);
                }
            }
        }
        __syncthreads();
        cur ^= 1;
    }

    // ---- cross-wave (k-parity) reduce via LDS, then kp==0 writes Ctx
    float* red = (float*)&Ksm[0][0];      // 16KB: 2 q-halves x 8KB
    if (kp == 1) {
#pragma unroll
        for (int dt = 0; dt < 2; ++dt)
#pragma unroll
            for (int m2 = 0; m2 < 16; ++m2)
                red[qh * 2048 + (dt * 16 + m2) * 64 + lane] = accd[dt][m2];
    }
    __syncthreads();
    if (kp == 0) {
#pragma unroll
        for (int dt = 0; dt < 2; ++dt)
#pragma unroll
            for (int m2 = 0; m2 < 16; ++m2) {
                const float v = accd[dt][m2] + red[qh * 2048 + (dt * 16 + m2) * 64 + lane];
                const int q = qw + (m2 & 3) + 8 * (m2 >> 2) + 4 * hl;
                const int d = dt * 32 + l31;
                Ctx[(size_t)(b * SS + q) * DD + h * 64 + d] = __float2bfloat16(v);
            }
    }
}

// ---------------------------------------------------------------
extern "C" void kernel_launch(void* const* d_in, const int* in_sizes, int n_in,
                              void* d_out, int out_size, void* d_ws, size_t ws_size,
                              hipStream_t stream) {
    const float* X  = (const float*)d_in[0];
    const int* masks = (const int*)d_in[1];
    const float* Wq = (const float*)d_in[2];
    const float* Wk = (const float*)d_in[3];
    const float* Wv = (const float*)d_in[4];
    const float* Wo = (const float*)d_in[5];
    float* out = (float*)d_out;
    char* ws = (char*)d_ws;

    const size_t MB = 1024 * 1024;
    bf* Xb   = (bf*)(ws);              // 8 MB  [B*S, D]
    bf* Wqkv = (bf*)(ws + 8  * MB);    // 6 MB  [3072, 1024]
    bf* Wob  = (bf*)(ws + 14 * MB);    // 2 MB
    bf* Qn   = (bf*)(ws + 16 * MB);    // 8 MB  [B*H, S, 64]
    bf* Kn   = (bf*)(ws + 24 * MB);
    bf* Vt   = (bf*)(ws + 32 * MB);    // 8 MB  [B*H, 64, S]
    bf* Ctx  = (bf*)(ws + 40 * MB);    // 8 MB  [B*S, D]

    // converts (one launch)
    k_convert<<<8192, 256, 0, stream>>>(X, Wq, Wk, Wv, Wo, Xb, Wqkv, Wob);

    // fused QKV projection + norm/mask epilogue + V-transpose (768 blocks)
    k_gemm<1, 128, 128><<<(ND3 / 128) * (MMR / 128), 256, 0, stream>>>(
        Xb, Wqkv, nullptr, masks, Qn, Kn, Vt, ND3 / 128, ND3, DD);

    // attention
    k_attn<<<1024, 256, 0, stream>>>(Qn, Kn, Vt, Ctx);

    // output projection (64x128 tiles -> 512 blocks, 2/CU)
    k_gemm<0, 64, 128><<<(DD / 128) * (MMR / 64), 256, 0, stream>>>(
        Ctx, Wob, out, nullptr, nullptr, nullptr, nullptr, DD / 128, DD, DD);
}